// Round 1
// baseline (2227.858 us; speedup 1.0000x reference)
//
#include <hip/hip_runtime.h>
#include <math.h>

#define CDIM 384
#define C3   1152
#define HH   128
#define WW   128
#define NPIX 16384
#define NHEADS 8
#define CPH  48

// ---------------- conv1x1 (GEMM): Y[z][m][n] = sum_k W[m][k] * X[z][k][n] ----------------
// X zstride = Cin*NPIX, Y zstride = Cout*NPIX. 64x64 tile, 256 thr, 4x4 per thread, K-tile 16.
__global__ __launch_bounds__(256) void conv1x1_kernel(
    const float* __restrict__ X, const float* __restrict__ W,
    float* __restrict__ Y, int Cin, int Cout)
{
    const int n0 = blockIdx.x * 64;
    const int m0 = blockIdx.y * 64;
    const int z  = blockIdx.z;
    const float* x = X + (size_t)z * Cin * NPIX;
    float*       y = Y + (size_t)z * Cout * NPIX;
    const int tid = threadIdx.x;
    const int tx = tid & 15, ty = tid >> 4;

    __shared__ float a_s[16][64];  // [k][m] = W[m0+m][k0+k]
    __shared__ float b_s[16][64];  // [k][n] = X[k0+k][n0+n]

    float acc[4][4] = {};
    for (int k0 = 0; k0 < Cin; k0 += 16) {
        {   // A tile: 64x16, float4 per thread along k
            int m = tid >> 2, k = (tid & 3) << 2;
            float4 av = *(const float4*)&W[(size_t)(m0 + m) * Cin + k0 + k];
            a_s[k + 0][m] = av.x; a_s[k + 1][m] = av.y;
            a_s[k + 2][m] = av.z; a_s[k + 3][m] = av.w;
        }
        {   // B tile: 16x64, float4 per thread along n
            int k = tid >> 4, n = (tid & 15) << 2;
            *(float4*)&b_s[k][n] = *(const float4*)&x[(size_t)(k0 + k) * NPIX + n0 + n];
        }
        __syncthreads();
        #pragma unroll
        for (int k = 0; k < 16; ++k) {
            float4 av = *(const float4*)&a_s[k][ty << 2];
            float4 bv = *(const float4*)&b_s[k][tx << 2];
            float a[4] = {av.x, av.y, av.z, av.w};
            float b[4] = {bv.x, bv.y, bv.z, bv.w};
            #pragma unroll
            for (int i = 0; i < 4; ++i)
                #pragma unroll
                for (int j = 0; j < 4; ++j)
                    acc[i][j] = fmaf(a[i], b[j], acc[i][j]);
        }
        __syncthreads();
    }
    #pragma unroll
    for (int i = 0; i < 4; ++i) {
        float4 o = make_float4(acc[i][0], acc[i][1], acc[i][2], acc[i][3]);
        *(float4*)&y[(size_t)(m0 + (ty << 2) + i) * NPIX + n0 + (tx << 2)] = o;
    }
}

// ---------------- depthwise 3x3, SAME padding ----------------
// MODE 0: plain, 1: gelu(exact) applied to result, 2: accumulate into Y (Y += conv)
template<int MODE>
__global__ __launch_bounds__(256) void dwconv_kernel(
    const float* __restrict__ X, const float* __restrict__ Wd,
    float* __restrict__ Y, size_t in_zstride, size_t out_zstride)
{
    const int z = blockIdx.z, c = blockIdx.y;
    const int p = blockIdx.x * 256 + threadIdx.x;
    const int yy = p >> 7, xx = p & 127;
    const float* xin = X + (size_t)z * in_zstride + (size_t)c * NPIX;
    float w[9];
    #pragma unroll
    for (int i = 0; i < 9; ++i) w[i] = Wd[c * 9 + i];
    float s = 0.f;
    #pragma unroll
    for (int dy = -1; dy <= 1; ++dy) {
        const int y2 = yy + dy;
        if (y2 < 0 || y2 >= HH) continue;
        #pragma unroll
        for (int dx = -1; dx <= 1; ++dx) {
            const int x2 = xx + dx;
            if (x2 < 0 || x2 >= WW) continue;
            s = fmaf(w[(dy + 1) * 3 + dx + 1], xin[y2 * WW + x2], s);
        }
    }
    float* yo = Y + (size_t)z * out_zstride + (size_t)c * NPIX + p;
    if (MODE == 1) s = 0.5f * s * (1.0f + erff(s * 0.70710678118654752f));
    if (MODE == 2) s += *yo;
    *yo = s;
}

// ---------------- per-(b, q/k, channel) L2 norm over N ----------------
__global__ __launch_bounds__(256) void l2norm_kernel(
    const float* __restrict__ QKdw, float* __restrict__ norms)
{
    const int z = blockIdx.z, t = blockIdx.y, ch = blockIdx.x;
    const float4* p = (const float4*)(QKdw + ((size_t)z * C3 + t * CDIM + ch) * NPIX);
    float s = 0.f;
    for (int i = threadIdx.x; i < NPIX / 4; i += 256) {
        float4 v = p[i];
        s += v.x * v.x + v.y * v.y + v.z * v.z + v.w * v.w;
    }
    #pragma unroll
    for (int off = 32; off; off >>= 1) s += __shfl_xor(s, off, 64);
    __shared__ float red[4];
    if ((threadIdx.x & 63) == 0) red[threadIdx.x >> 6] = s;
    __syncthreads();
    if (threadIdx.x == 0)
        norms[((size_t)z * 2 + t) * CDIM + ch] = sqrtf(red[0] + red[1] + red[2] + red[3]);
}

// ---------------- raw attention scores S[b,h,c,d] = sum_n q[c,n]*k[d,n] ----------------
// grid (32 K-chunks of 512, heads, nb); 3x3 per thread register block; atomicAdd partials.
__global__ __launch_bounds__(256) void scores_kernel(
    const float* __restrict__ QKdw, float* __restrict__ S)
{
    const int z = blockIdx.z, h = blockIdx.y, chunk = blockIdx.x;
    const float* qb = QKdw + ((size_t)z * C3 + h * CPH) * NPIX;
    const float* kb = qb + (size_t)CDIM * NPIX;
    __shared__ float qs[48][68];   // stride 68: 16B-aligned rows, <=2-way bank aliasing
    __shared__ float ks[48][68];
    const int tid = threadIdx.x;
    const int ti = tid >> 4, tj = tid & 15;

    float acc[3][3] = {};
    for (int nt = 0; nt < 8; ++nt) {
        const int nbase = chunk * 512 + nt * 64;
        #pragma unroll
        for (int t2 = 0; t2 < 12; ++t2) {
            int e = tid + t2 * 256;
            int cc = e >> 6, nn = e & 63;
            qs[cc][nn] = qb[(size_t)cc * NPIX + nbase + nn];
            ks[cc][nn] = kb[(size_t)cc * NPIX + nbase + nn];
        }
        __syncthreads();
        #pragma unroll
        for (int n4 = 0; n4 < 16; ++n4) {
            float4 qa[3], kv[3];
            #pragma unroll
            for (int i = 0; i < 3; ++i) qa[i] = *(const float4*)&qs[ti * 3 + i][n4 << 2];
            #pragma unroll
            for (int j = 0; j < 3; ++j) kv[j] = *(const float4*)&ks[tj * 3 + j][n4 << 2];
            #pragma unroll
            for (int i = 0; i < 3; ++i)
                #pragma unroll
                for (int j = 0; j < 3; ++j)
                    acc[i][j] += qa[i].x * kv[j].x + qa[i].y * kv[j].y
                               + qa[i].z * kv[j].z + qa[i].w * kv[j].w;
        }
        __syncthreads();
    }
    float* Sb = S + (size_t)(z * NHEADS + h) * CPH * CPH;
    #pragma unroll
    for (int i = 0; i < 3; ++i)
        #pragma unroll
        for (int j = 0; j < 3; ++j)
            atomicAdd(&Sb[(ti * 3 + i) * CPH + tj * 3 + j], acc[i][j]);
}

// ---------------- dual softmax blend (in-place on S) ----------------
__global__ __launch_bounds__(64) void softmax_kernel(
    float* __restrict__ S, const float* __restrict__ norms,
    const int* __restrict__ mask, const float* __restrict__ temp,
    const float* __restrict__ wblend)
{
    const int z = blockIdx.z, h = blockIdx.y, c = blockIdx.x;
    const int d = threadIdx.x;
    float* Srow = S + ((size_t)(z * NHEADS + h) * CPH + c) * CPH;
    const float nq = fmaxf(norms[((size_t)z * 2 + 0) * CDIM + h * CPH + c], 1e-12f);
    float a0 = -INFINITY, a1 = -INFINITY;
    if (d < CPH) {
        const float nk = fmaxf(norms[((size_t)z * 2 + 1) * CDIM + h * CPH + d], 1e-12f);
        a0 = Srow[d] / (nq * nk) * temp[h];
        a1 = (mask[(h * CPH + c) * CPH + d] == 0) ? -1e9f : a0;
    }
    float m0 = a0, m1 = a1;
    #pragma unroll
    for (int off = 32; off; off >>= 1) {
        m0 = fmaxf(m0, __shfl_xor(m0, off, 64));
        m1 = fmaxf(m1, __shfl_xor(m1, off, 64));
    }
    float e0 = (d < CPH) ? expf(a0 - m0) : 0.f;
    float e1 = (d < CPH) ? expf(a1 - m1) : 0.f;
    float s0 = e0, s1 = e1;
    #pragma unroll
    for (int off = 32; off; off >>= 1) {
        s0 += __shfl_xor(s0, off, 64);
        s1 += __shfl_xor(s1, off, 64);
    }
    const float b0 = wblend[0], b1 = wblend[1];
    const float bm = fmaxf(b0, b1);
    const float eb0 = expf(b0 - bm), eb1 = expf(b1 - bm);
    const float ws0 = eb0 / (eb0 + eb1), ws1 = eb1 / (eb0 + eb1);
    if (d < CPH) Srow[d] = (e0 / s0) * ws0 + (e1 / s1) * ws1;
}

// ---------------- out[b,h*48+c,n] = sum_d attn[c,d] * v[d,n] ----------------
__global__ __launch_bounds__(256) void attnv_kernel(
    const float* __restrict__ A, const float* __restrict__ QKdw, float* __restrict__ O)
{
    const int z = blockIdx.z, h = blockIdx.y;
    const int n = blockIdx.x * 256 + threadIdx.x;
    const float* vb = QKdw + ((size_t)z * C3 + 2 * CDIM + h * CPH) * NPIX;
    float* ob = O + ((size_t)z * CDIM + h * CPH) * NPIX;
    __shared__ float as[48][48];
    const float* Ab = A + (size_t)(z * NHEADS + h) * CPH * CPH;
    for (int e = threadIdx.x; e < CPH * CPH; e += 256) as[e / 48][e % 48] = Ab[e];
    __syncthreads();
    float v[48];
    #pragma unroll
    for (int d = 0; d < 48; ++d) v[d] = vb[(size_t)d * NPIX + n];
    #pragma unroll 1
    for (int c = 0; c < 48; ++c) {
        float s = 0.f;
        #pragma unroll
        for (int d = 0; d < 48; ++d) s = fmaf(as[c][d], v[d], s);
        ob[(size_t)c * NPIX + n] = s;
    }
}

extern "C" void kernel_launch(void* const* d_in, const int* in_sizes, int n_in,
                              void* d_out, int out_size, void* d_ws, size_t ws_size,
                              hipStream_t stream)
{
    const float* x      = (const float*)d_in[0];
    const int*   mask   = (const int*)d_in[1];
    const float* qkv_w  = (const float*)d_in[2];
    const float* dw_w   = (const float*)d_in[3];
    const float* proj_w = (const float*)d_in[4];
    const float* temp   = (const float*)d_in[5];
    const float* wblend = (const float*)d_in[6];
    const float* pos_w1 = (const float*)d_in[7];
    const float* pos_w2 = (const float*)d_in[8];
    float* out = (float*)d_out;

    const int B = 4;
    const size_t big = (size_t)C3 * NPIX;
    auto need = [](int nb) {
        return (size_t)nb * ((size_t)2 * C3 * NPIX + NHEADS * CPH * CPH + 2 * CDIM)
               * sizeof(float);
    };
    int nb = 4;
    if (need(4) > ws_size) nb = (need(2) <= ws_size) ? 2 : 1;

    float* w_qkv0  = (float*)d_ws;                                   // nb * 1152 * N
    float* w_qkvdw = w_qkv0 + (size_t)nb * big;                      // nb * 1152 * N
    float* w_S     = w_qkvdw + (size_t)nb * big;                     // nb * 8 * 48 * 48
    float* w_norms = w_S + (size_t)nb * NHEADS * CPH * CPH;          // nb * 2 * 384
    float* w_oattn = w_qkv0;                                         // alias (qkv0 dead)
    float* w_t1    = w_qkv0 + (size_t)nb * CDIM * NPIX;              // alias

    for (int b0 = 0; b0 < B; b0 += nb) {
        const float* xb = x + (size_t)b0 * CDIM * NPIX;
        float* outb = out + (size_t)b0 * CDIM * NPIX;

        // 1) qkv 1x1 conv (GEMM 1152x384 x N)
        conv1x1_kernel<<<dim3(NPIX / 64, C3 / 64, nb), 256, 0, stream>>>(
            xb, qkv_w, w_qkv0, CDIM, C3);
        // 2) depthwise 3x3 on all 1152 channels
        dwconv_kernel<0><<<dim3(NPIX / 256, C3, nb), 256, 0, stream>>>(
            w_qkv0, dw_w, w_qkvdw, big, big);
        // 3) L2 norms of q and k rows
        l2norm_kernel<<<dim3(CDIM, 2, nb), 256, 0, stream>>>(w_qkvdw, w_norms);
        // 4) raw scores (atomic partials over 32 K-chunks)
        hipMemsetAsync(w_S, 0, (size_t)nb * NHEADS * CPH * CPH * sizeof(float), stream);
        scores_kernel<<<dim3(32, NHEADS, nb), 256, 0, stream>>>(w_qkvdw, w_S);
        // 5) normalize + temperature + dual softmax blend (in place)
        softmax_kernel<<<dim3(CPH, NHEADS, nb), 64, 0, stream>>>(
            w_S, w_norms, mask, temp, wblend);
        // 6) attn @ v
        attnv_kernel<<<dim3(NPIX / 256, NHEADS, nb), 256, 0, stream>>>(
            w_S, w_qkvdw, w_oattn);
        // 7) proj 1x1 conv -> d_out
        conv1x1_kernel<<<dim3(NPIX / 64, CDIM / 64, nb), 256, 0, stream>>>(
            w_oattn, proj_w, outb, CDIM, CDIM);
        // 8) pos branch: dw3x3 + exact gelu
        dwconv_kernel<1><<<dim3(NPIX / 256, CDIM, nb), 256, 0, stream>>>(
            w_qkvdw + (size_t)2 * CDIM * NPIX, pos_w1, w_t1, big, (size_t)CDIM * NPIX);
        // 9) dw3x3 and accumulate into d_out
        dwconv_kernel<2><<<dim3(NPIX / 256, CDIM, nb), 256, 0, stream>>>(
            w_t1, pos_w2, outb, (size_t)CDIM * NPIX, (size_t)CDIM * NPIX);
    }
}

// Round 2
// 1158.807 us; speedup vs baseline: 1.9225x; 1.9225x over previous
//
#include <hip/hip_runtime.h>
#include <math.h>

#define CDIM 384
#define C3   1152
#define HH   128
#define WW   128
#define NPIX 16384
#define NHEADS 8
#define CPH  48

typedef short bf16x8 __attribute__((ext_vector_type(8)));
typedef float f32x4  __attribute__((ext_vector_type(4)));

__device__ __forceinline__ float bf2f(unsigned short h) {
    union { unsigned u; float f; } x; x.u = ((unsigned)h) << 16; return x.f;
}
__device__ __forceinline__ unsigned short f2bf(float f) {
    union { float f; unsigned u; } x; x.f = f;
    unsigned r = x.u + 0x7fffu + ((x.u >> 16) & 1u);
    return (unsigned short)(r >> 16);
}

#define ASYNC_CP16(gp, lp) \
    __builtin_amdgcn_global_load_lds( \
        (const __attribute__((address_space(1))) unsigned int*)(gp), \
        (__attribute__((address_space(3))) unsigned int*)(lp), 16, 0, 0)

// ---------------- fp32 -> bf16 elementwise cast (weights) ----------------
__global__ __launch_bounds__(256) void cast_bf16_kernel(
    const float* __restrict__ in, unsigned short* __restrict__ out, int n4)
{
    int i = blockIdx.x * 256 + threadIdx.x;
    if (i < n4) {
        float4 v = *(const float4*)(in + (size_t)i * 4);
        ushort4 o = { f2bf(v.x), f2bf(v.y), f2bf(v.z), f2bf(v.w) };
        *(ushort4*)(out + (size_t)i * 4) = o;
    }
}

// ---------------- transpose [K=384][NPIX] -> bf16 [NPIX][384] ----------------
template<int IN_BF16>
__global__ __launch_bounds__(256) void transpose_kernel(
    const void* __restrict__ in_, unsigned short* __restrict__ out, size_t in_zstride)
{
    const int z = blockIdx.z;
    const int n0 = blockIdx.x * 64, k0 = blockIdx.y * 64;
    __shared__ unsigned short tile[64][69];
    const int t = threadIdx.x;
    if (IN_BF16) {
        const unsigned short* in = (const unsigned short*)in_ + (size_t)z * in_zstride;
        #pragma unroll
        for (int r = 0; r < 4; ++r) {
            int kk = r * 16 + (t >> 4), nn = (t & 15) * 4;
            ushort4 v = *(const ushort4*)(in + (size_t)(k0 + kk) * NPIX + n0 + nn);
            tile[kk][nn] = v.x; tile[kk][nn + 1] = v.y;
            tile[kk][nn + 2] = v.z; tile[kk][nn + 3] = v.w;
        }
    } else {
        const float* in = (const float*)in_ + (size_t)z * in_zstride;
        #pragma unroll
        for (int r = 0; r < 4; ++r) {
            int kk = r * 16 + (t >> 4), nn = (t & 15) * 4;
            float4 v = *(const float4*)(in + (size_t)(k0 + kk) * NPIX + n0 + nn);
            tile[kk][nn] = f2bf(v.x); tile[kk][nn + 1] = f2bf(v.y);
            tile[kk][nn + 2] = f2bf(v.z); tile[kk][nn + 3] = f2bf(v.w);
        }
    }
    __syncthreads();
    unsigned short* o = out + (size_t)z * NPIX * CDIM;
    #pragma unroll
    for (int r = 0; r < 2; ++r) {
        int nn = r * 32 + (t >> 3), kk = (t & 7) * 8;
        ushort4 a, b;
        a.x = tile[kk + 0][nn]; a.y = tile[kk + 1][nn];
        a.z = tile[kk + 2][nn]; a.w = tile[kk + 3][nn];
        b.x = tile[kk + 4][nn]; b.y = tile[kk + 5][nn];
        b.z = tile[kk + 6][nn]; b.w = tile[kk + 7][nn];
        *(ushort4*)(o + (size_t)(n0 + nn) * CDIM + k0 + kk) = a;
        *(ushort4*)(o + (size_t)(n0 + nn) * CDIM + k0 + kk + 4) = b;
    }
}

// ---------------- bf16 MFMA GEMM: C[z][m][n] = sum_k A[m][k] * Bt[z][n][k] ----------------
// A: bf16 [M][384] (optionally per-z), Bt: bf16 [z][NPIX][384], K=384.
// 128x128 tile, 256 thr (4 waves 2x2, each 64x64 = 4x4 MFMA 16x16x32), BK=32,
// global_load_lds width-16 staging (lane-order-contiguous LDS layout, m97 structure).
template<int OUT_BF16, int A_PER_Z>
__global__ __launch_bounds__(256) void mfma_gemm_kernel(
    const unsigned short* __restrict__ A, const unsigned short* __restrict__ Bt,
    void* __restrict__ C, int M)
{
    const int z = blockIdx.z;
    const int n0 = blockIdx.x * 128;
    const int m0 = blockIdx.y * 128;
    const unsigned short* a = A + (A_PER_Z ? (size_t)z * M * CDIM : 0);
    const unsigned short* bt = Bt + (size_t)z * NPIX * CDIM;
    const int t = threadIdx.x;
    const int wave = t >> 6, lane = t & 63;
    const int wm = (wave & 1) * 64, wn = (wave >> 1) * 64;
    const int lm = lane & 15, lq = lane >> 4;

    __shared__ unsigned short a_s[128 * 32];  // [m][k], rows of 64B
    __shared__ unsigned short b_s[128 * 32];  // [n][k]

    f32x4 acc[4][4];
    #pragma unroll
    for (int i = 0; i < 4; ++i)
        #pragma unroll
        for (int j = 0; j < 4; ++j)
            acc[i][j] = (f32x4){0.f, 0.f, 0.f, 0.f};

    const int srow = t >> 2, scol = (t & 3) * 8;

    for (int k0 = 0; k0 < CDIM; k0 += 32) {
        #pragma unroll
        for (int r = 0; r < 2; ++r)
            ASYNC_CP16(a + (size_t)(m0 + r * 64 + srow) * CDIM + k0 + scol,
                       a_s + (r * 64 + srow) * 32 + scol);
        #pragma unroll
        for (int r = 0; r < 2; ++r)
            ASYNC_CP16(bt + (size_t)(n0 + r * 64 + srow) * CDIM + k0 + scol,
                       b_s + (r * 64 + srow) * 32 + scol);
        __syncthreads();
        bf16x8 af[4], bfr[4];
        #pragma unroll
        for (int i = 0; i < 4; ++i)
            af[i] = *(const bf16x8*)(a_s + (wm + i * 16 + lm) * 32 + lq * 8);
        #pragma unroll
        for (int j = 0; j < 4; ++j)
            bfr[j] = *(const bf16x8*)(b_s + (wn + j * 16 + lm) * 32 + lq * 8);
        #pragma unroll
        for (int i = 0; i < 4; ++i)
            #pragma unroll
            for (int j = 0; j < 4; ++j)
                acc[i][j] = __builtin_amdgcn_mfma_f32_16x16x32_bf16(
                    af[i], bfr[j], acc[i][j], 0, 0, 0);
        __syncthreads();
    }

    if (OUT_BF16) {
        unsigned short* c = (unsigned short*)C + (size_t)z * M * NPIX;
        #pragma unroll
        for (int i = 0; i < 4; ++i)
            #pragma unroll
            for (int j = 0; j < 4; ++j) {
                size_t base = (size_t)(m0 + wm + i * 16 + lq * 4) * NPIX
                            + (n0 + wn + j * 16 + lm);
                #pragma unroll
                for (int r = 0; r < 4; ++r)
                    c[base + (size_t)r * NPIX] = f2bf(acc[i][j][r]);
            }
    } else {
        float* c = (float*)C + (size_t)z * M * NPIX;
        #pragma unroll
        for (int i = 0; i < 4; ++i)
            #pragma unroll
            for (int j = 0; j < 4; ++j) {
                size_t base = (size_t)(m0 + wm + i * 16 + lq * 4) * NPIX
                            + (n0 + wn + j * 16 + lm);
                #pragma unroll
                for (int r = 0; r < 4; ++r)
                    c[base + (size_t)r * NPIX] = acc[i][j][r];
            }
    }
}

// ---------------- depthwise 3x3 SAME, bf16 in. MODE 0: ->bf16, 1: gelu->bf16, 2: +=fp32 out ----
template<int MODE>
__global__ __launch_bounds__(256) void dwconv_bf_kernel(
    const unsigned short* __restrict__ X, const float* __restrict__ Wd,
    void* __restrict__ Y, size_t in_zstride, size_t out_zstride)
{
    const int z = blockIdx.z, c = blockIdx.y;
    const int p = blockIdx.x * 256 + threadIdx.x;
    const int yy = p >> 7, xx = p & 127;
    const unsigned short* xin = X + (size_t)z * in_zstride + (size_t)c * NPIX;
    float w[9];
    #pragma unroll
    for (int i = 0; i < 9; ++i) w[i] = Wd[c * 9 + i];
    float s = 0.f;
    #pragma unroll
    for (int dy = -1; dy <= 1; ++dy) {
        const int y2 = yy + dy;
        if (y2 < 0 || y2 >= HH) continue;
        #pragma unroll
        for (int dx = -1; dx <= 1; ++dx) {
            const int x2 = xx + dx;
            if (x2 < 0 || x2 >= WW) continue;
            s = fmaf(w[(dy + 1) * 3 + dx + 1], bf2f(xin[y2 * WW + x2]), s);
        }
    }
    if (MODE == 1) s = 0.5f * s * (1.0f + erff(s * 0.70710678118654752f));
    if (MODE <= 1) {
        ((unsigned short*)Y)[(size_t)z * out_zstride + (size_t)c * NPIX + p] = f2bf(s);
    } else {
        float* yo = (float*)Y + (size_t)z * out_zstride + (size_t)c * NPIX + p;
        *yo += s;
    }
}

// ---------------- per-(b, q/k, channel) L2 norm over N (bf16 input) ----------------
__global__ __launch_bounds__(256) void l2norm_bf_kernel(
    const unsigned short* __restrict__ QKdw, float* __restrict__ norms)
{
    const int z = blockIdx.z, t = blockIdx.y, ch = blockIdx.x;
    const uint4* p4 = (const uint4*)(QKdw + ((size_t)z * C3 + t * CDIM + ch) * NPIX);
    float s = 0.f;
    for (int i = threadIdx.x; i < NPIX / 8; i += 256) {
        uint4 v = p4[i];
        float a0 = bf2f(v.x & 0xffff), a1 = bf2f(v.x >> 16);
        float a2 = bf2f(v.y & 0xffff), a3 = bf2f(v.y >> 16);
        float a4 = bf2f(v.z & 0xffff), a5 = bf2f(v.z >> 16);
        float a6 = bf2f(v.w & 0xffff), a7 = bf2f(v.w >> 16);
        s += a0*a0 + a1*a1 + a2*a2 + a3*a3 + a4*a4 + a5*a5 + a6*a6 + a7*a7;
    }
    #pragma unroll
    for (int off = 32; off; off >>= 1) s += __shfl_xor(s, off, 64);
    __shared__ float red[4];
    if ((threadIdx.x & 63) == 0) red[threadIdx.x >> 6] = s;
    __syncthreads();
    if (threadIdx.x == 0)
        norms[((size_t)z * 2 + t) * CDIM + ch] = sqrtf(red[0] + red[1] + red[2] + red[3]);
}

// ---------------- scores via MFMA, fragments straight from global (K-contiguous) ----------
__global__ __launch_bounds__(256) void scores_mfma_kernel(
    const unsigned short* __restrict__ QKdw, float* __restrict__ S)
{
    const int z = blockIdx.z, h = blockIdx.y, chunk = blockIdx.x;
    const unsigned short* qb = QKdw + ((size_t)z * C3 + h * CPH) * NPIX;
    const unsigned short* kb = qb + (size_t)CDIM * NPIX;
    const int t = threadIdx.x, wave = t >> 6, lane = t & 63;
    const int lm = lane & 15, lq = lane >> 4;
    const int kw0 = chunk * 2048 + wave * 512;

    f32x4 acc[3][3];
    #pragma unroll
    for (int i = 0; i < 3; ++i)
        #pragma unroll
        for (int j = 0; j < 3; ++j)
            acc[i][j] = (f32x4){0.f, 0.f, 0.f, 0.f};

    for (int ks = 0; ks < 512; ks += 32) {
        const int kk = kw0 + ks + lq * 8;
        bf16x8 af[3], bfr[3];
        #pragma unroll
        for (int i = 0; i < 3; ++i)
            af[i] = *(const bf16x8*)(qb + (size_t)(i * 16 + lm) * NPIX + kk);
        #pragma unroll
        for (int j = 0; j < 3; ++j)
            bfr[j] = *(const bf16x8*)(kb + (size_t)(j * 16 + lm) * NPIX + kk);
        #pragma unroll
        for (int i = 0; i < 3; ++i)
            #pragma unroll
            for (int j = 0; j < 3; ++j)
                acc[i][j] = __builtin_amdgcn_mfma_f32_16x16x32_bf16(
                    af[i], bfr[j], acc[i][j], 0, 0, 0);
    }
    __shared__ float s_red[CPH * CPH];
    for (int e = t; e < CPH * CPH; e += 256) s_red[e] = 0.f;
    __syncthreads();
    #pragma unroll
    for (int i = 0; i < 3; ++i)
        #pragma unroll
        for (int j = 0; j < 3; ++j)
            #pragma unroll
            for (int r = 0; r < 4; ++r)
                atomicAdd(&s_red[(i * 16 + lq * 4 + r) * CPH + j * 16 + lm], acc[i][j][r]);
    __syncthreads();
    float* Sb = S + (size_t)(z * NHEADS + h) * CPH * CPH;
    for (int e = t; e < CPH * CPH; e += 256) atomicAdd(&Sb[e], s_red[e]);
}

// ---------------- dual softmax blend (in-place on S) ----------------
__global__ __launch_bounds__(64) void softmax_kernel(
    float* __restrict__ S, const float* __restrict__ norms,
    const int* __restrict__ mask, const float* __restrict__ temp,
    const float* __restrict__ wblend)
{
    const int z = blockIdx.z, h = blockIdx.y, c = blockIdx.x;
    const int d = threadIdx.x;
    float* Srow = S + ((size_t)(z * NHEADS + h) * CPH + c) * CPH;
    const float nq = fmaxf(norms[((size_t)z * 2 + 0) * CDIM + h * CPH + c], 1e-12f);
    float a0 = -INFINITY, a1 = -INFINITY;
    if (d < CPH) {
        const float nk = fmaxf(norms[((size_t)z * 2 + 1) * CDIM + h * CPH + d], 1e-12f);
        a0 = Srow[d] / (nq * nk) * temp[h];
        a1 = (mask[(h * CPH + c) * CPH + d] == 0) ? -1e9f : a0;
    }
    float m0 = a0, m1 = a1;
    #pragma unroll
    for (int off = 32; off; off >>= 1) {
        m0 = fmaxf(m0, __shfl_xor(m0, off, 64));
        m1 = fmaxf(m1, __shfl_xor(m1, off, 64));
    }
    float e0 = (d < CPH) ? expf(a0 - m0) : 0.f;
    float e1 = (d < CPH) ? expf(a1 - m1) : 0.f;
    float s0 = e0, s1 = e1;
    #pragma unroll
    for (int off = 32; off; off >>= 1) {
        s0 += __shfl_xor(s0, off, 64);
        s1 += __shfl_xor(s1, off, 64);
    }
    const float b0 = wblend[0], b1 = wblend[1];
    const float bm = fmaxf(b0, b1);
    const float eb0 = expf(b0 - bm), eb1 = expf(b1 - bm);
    const float ws0 = eb0 / (eb0 + eb1), ws1 = eb1 / (eb0 + eb1);
    if (d < CPH) Srow[d] = (e0 / s0) * ws0 + (e1 / s1) * ws1;
}

// ---------------- Mcat[z][:, h*48+d] = P[:, h*48+c] @ A_h[c][d]  (fold proj into attn) -----
__global__ __launch_bounds__(256) void mproj_kernel(
    const float* __restrict__ S, const float* __restrict__ P,
    unsigned short* __restrict__ Mcat)
{
    const int z = blockIdx.y, h = blockIdx.x;
    __shared__ float As[CPH * CPH];
    const float* Sb = S + (size_t)(z * NHEADS + h) * CPH * CPH;
    for (int e = threadIdx.x; e < CPH * CPH; e += 256) As[e] = Sb[e];
    __syncthreads();
    unsigned short* Mz = Mcat + (size_t)z * CDIM * CDIM;
    for (int e = threadIdx.x; e < CDIM * CPH; e += 256) {
        const int m = e / CPH, d = e % CPH;
        const float* pr = P + (size_t)m * CDIM + h * CPH;
        float s = 0.f;
        #pragma unroll
        for (int c = 0; c < CPH; ++c) s = fmaf(pr[c], As[c * CPH + d], s);
        Mz[(size_t)m * CDIM + h * CPH + d] = f2bf(s);
    }
}

extern "C" void kernel_launch(void* const* d_in, const int* in_sizes, int n_in,
                              void* d_out, int out_size, void* d_ws, size_t ws_size,
                              hipStream_t stream)
{
    const float* x      = (const float*)d_in[0];
    const int*   mask   = (const int*)d_in[1];
    const float* qkv_w  = (const float*)d_in[2];
    const float* dw_w   = (const float*)d_in[3];
    const float* proj_w = (const float*)d_in[4];
    const float* temp   = (const float*)d_in[5];
    const float* wblend = (const float*)d_in[6];
    const float* pos_w1 = (const float*)d_in[7];
    const float* pos_w2 = (const float*)d_in[8];
    float* out = (float*)d_out;

    auto need = [](size_t nb) {
        return nb * ((size_t)NPIX * CDIM * 2      // x_t
                   + (size_t)C3 * NPIX * 2        // qkv0 (reused for v_t + t1)
                   + (size_t)C3 * NPIX * 2        // qkvdw
                   + (size_t)NHEADS * CPH * CPH * 4
                   + (size_t)2 * CDIM * 4
                   + (size_t)CDIM * CDIM * 2)
             + (size_t)C3 * CDIM * 2;             // w_bf
    };
    int nb = 4;
    if (need(4) > ws_size) nb = (need(2) <= ws_size) ? 2 : 1;

    char* p = (char*)d_ws;
    unsigned short* w_bf  = (unsigned short*)p; p += (size_t)C3 * CDIM * 2;
    unsigned short* x_t   = (unsigned short*)p; p += (size_t)nb * NPIX * CDIM * 2;
    unsigned short* qkv0  = (unsigned short*)p; p += (size_t)nb * C3 * NPIX * 2;
    unsigned short* qkvdw = (unsigned short*)p; p += (size_t)nb * C3 * NPIX * 2;
    float* S     = (float*)p; p += (size_t)nb * NHEADS * CPH * CPH * 4;
    float* norms = (float*)p; p += (size_t)nb * 2 * CDIM * 4;
    unsigned short* Mcat = (unsigned short*)p;
    unsigned short* v_t = qkv0;                                  // alias: qkv0 dead by then
    unsigned short* t1  = qkv0 + (size_t)nb * NPIX * CDIM;       // alias

    cast_bf16_kernel<<<dim3(C3 * CDIM / 4 / 256), 256, 0, stream>>>(qkv_w, w_bf, C3 * CDIM / 4);

    for (int b0 = 0; b0 < 4; b0 += nb) {
        const float* xb = x + (size_t)b0 * CDIM * NPIX;
        float* outb = out + (size_t)b0 * CDIM * NPIX;

        // x -> bf16 x^T [n][k]
        transpose_kernel<0><<<dim3(NPIX / 64, CDIM / 64, nb), 256, 0, stream>>>(
            xb, x_t, (size_t)CDIM * NPIX);
        // qkv 1x1 conv: bf16 MFMA GEMM -> qkv0 bf16
        mfma_gemm_kernel<1, 0><<<dim3(NPIX / 128, C3 / 128, nb), 256, 0, stream>>>(
            w_bf, x_t, qkv0, C3);
        // depthwise 3x3 on 1152 ch -> qkvdw bf16
        dwconv_bf_kernel<0><<<dim3(NPIX / 256, C3, nb), 256, 0, stream>>>(
            qkv0, dw_w, qkvdw, (size_t)C3 * NPIX, (size_t)C3 * NPIX);
        // L2 norms of q,k rows
        l2norm_bf_kernel<<<dim3(CDIM, 2, nb), 256, 0, stream>>>(qkvdw, norms);
        // raw scores
        hipMemsetAsync(S, 0, (size_t)nb * NHEADS * CPH * CPH * 4, stream);
        scores_mfma_kernel<<<dim3(8, NHEADS, nb), 256, 0, stream>>>(qkvdw, S);
        // dual-softmax blend
        softmax_kernel<<<dim3(CPH, NHEADS, nb), 64, 0, stream>>>(
            S, norms, mask, temp, wblend);
        // fold proj into attn: Mcat = [P_h @ A_h]
        mproj_kernel<<<dim3(NHEADS, nb), 256, 0, stream>>>(S, proj_w, Mcat);
        // v -> bf16 v^T [n][k]
        transpose_kernel<1><<<dim3(NPIX / 64, CDIM / 64, nb), 256, 0, stream>>>(
            qkvdw + (size_t)2 * CDIM * NPIX, v_t, (size_t)C3 * NPIX);
        // fused attn@v + proj: out = Mcat @ v  (fp32 out, direct to d_out)
        mfma_gemm_kernel<0, 1><<<dim3(NPIX / 128, CDIM / 128, nb), 256, 0, stream>>>(
            Mcat, v_t, outb, CDIM);
        // pos branch: dw3x3 + gelu -> t1 bf16
        dwconv_bf_kernel<1><<<dim3(NPIX / 256, CDIM, nb), 256, 0, stream>>>(
            qkvdw + (size_t)2 * CDIM * NPIX, pos_w1, t1, (size_t)C3 * NPIX, (size_t)CDIM * NPIX);
        // dw3x3, accumulate into d_out
        dwconv_bf_kernel<2><<<dim3(NPIX / 256, CDIM, nb), 256, 0, stream>>>(
            t1, pos_w2, outb, (size_t)CDIM * NPIX, (size_t)CDIM * NPIX);
    }
}

// Round 3
// 575.776 us; speedup vs baseline: 3.8693x; 2.0126x over previous
//
#include <hip/hip_runtime.h>
#include <math.h>

#define CDIM 384
#define C3   1152
#define HH   128
#define WW   128
#define NPIX 16384
#define NHEADS 8
#define CPH  48

typedef short bf16x8 __attribute__((ext_vector_type(8)));
typedef float f32x4  __attribute__((ext_vector_type(4)));
typedef unsigned short u16x8 __attribute__((ext_vector_type(8)));

__device__ __forceinline__ float bf2f(unsigned short h) {
    union { unsigned u; float f; } x; x.u = ((unsigned)h) << 16; return x.f;
}
__device__ __forceinline__ unsigned short f2bf(float f) {
    union { float f; unsigned u; } x; x.f = f;
    unsigned r = x.u + 0x7fffu + ((x.u >> 16) & 1u);
    return (unsigned short)(r >> 16);
}

#define ASYNC_CP16(gp, lp) \
    __builtin_amdgcn_global_load_lds( \
        (const __attribute__((address_space(1))) unsigned int*)(gp), \
        (__attribute__((address_space(3))) unsigned int*)(lp), 16, 0, 0)

// ---------------- fp32 -> bf16 elementwise cast (weights) ----------------
__global__ __launch_bounds__(256) void cast_bf16_kernel(
    const float* __restrict__ in, unsigned short* __restrict__ out, int n4)
{
    int i = blockIdx.x * 256 + threadIdx.x;
    if (i < n4) {
        float4 v = *(const float4*)(in + (size_t)i * 4);
        ushort4 o = { f2bf(v.x), f2bf(v.y), f2bf(v.z), f2bf(v.w) };
        *(ushort4*)(out + (size_t)i * 4) = o;
    }
}

// ---------------- transpose [K=384][NPIX] -> bf16 [NPIX][384] ----------------
template<int IN_BF16>
__global__ __launch_bounds__(256) void transpose_kernel(
    const void* __restrict__ in_, unsigned short* __restrict__ out, size_t in_zstride)
{
    const int z = blockIdx.z;
    const int n0 = blockIdx.x * 64, k0 = blockIdx.y * 64;
    __shared__ unsigned short tile[64][69];
    const int t = threadIdx.x;
    if (IN_BF16) {
        const unsigned short* in = (const unsigned short*)in_ + (size_t)z * in_zstride;
        #pragma unroll
        for (int r = 0; r < 4; ++r) {
            int kk = r * 16 + (t >> 4), nn = (t & 15) * 4;
            ushort4 v = *(const ushort4*)(in + (size_t)(k0 + kk) * NPIX + n0 + nn);
            tile[kk][nn] = v.x; tile[kk][nn + 1] = v.y;
            tile[kk][nn + 2] = v.z; tile[kk][nn + 3] = v.w;
        }
    } else {
        const float* in = (const float*)in_ + (size_t)z * in_zstride;
        #pragma unroll
        for (int r = 0; r < 4; ++r) {
            int kk = r * 16 + (t >> 4), nn = (t & 15) * 4;
            float4 v = *(const float4*)(in + (size_t)(k0 + kk) * NPIX + n0 + nn);
            tile[kk][nn] = f2bf(v.x); tile[kk][nn + 1] = f2bf(v.y);
            tile[kk][nn + 2] = f2bf(v.z); tile[kk][nn + 3] = f2bf(v.w);
        }
    }
    __syncthreads();
    unsigned short* o = out + (size_t)z * NPIX * CDIM;
    #pragma unroll
    for (int r = 0; r < 2; ++r) {
        int nn = r * 32 + (t >> 3), kk = (t & 7) * 8;
        ushort4 a, b;
        a.x = tile[kk + 0][nn]; a.y = tile[kk + 1][nn];
        a.z = tile[kk + 2][nn]; a.w = tile[kk + 3][nn];
        b.x = tile[kk + 4][nn]; b.y = tile[kk + 5][nn];
        b.z = tile[kk + 6][nn]; b.w = tile[kk + 7][nn];
        *(ushort4*)(o + (size_t)(n0 + nn) * CDIM + k0 + kk) = a;
        *(ushort4*)(o + (size_t)(n0 + nn) * CDIM + k0 + kk + 4) = b;
    }
}

// ---------------- bf16 MFMA GEMM: C[z][m][n] = sum_k A[m][k] * Bt[z][n][k] ----------------
template<int OUT_BF16, int A_PER_Z>
__global__ __launch_bounds__(256) void mfma_gemm_kernel(
    const unsigned short* __restrict__ A, const unsigned short* __restrict__ Bt,
    void* __restrict__ C, int M)
{
    const int z = blockIdx.z;
    const int n0 = blockIdx.x * 128;
    const int m0 = blockIdx.y * 128;
    const unsigned short* a = A + (A_PER_Z ? (size_t)z * M * CDIM : 0);
    const unsigned short* bt = Bt + (size_t)z * NPIX * CDIM;
    const int t = threadIdx.x;
    const int wave = t >> 6, lane = t & 63;
    const int wm = (wave & 1) * 64, wn = (wave >> 1) * 64;
    const int lm = lane & 15, lq = lane >> 4;

    __shared__ unsigned short a_s[128 * 32];
    __shared__ unsigned short b_s[128 * 32];

    f32x4 acc[4][4];
    #pragma unroll
    for (int i = 0; i < 4; ++i)
        #pragma unroll
        for (int j = 0; j < 4; ++j)
            acc[i][j] = (f32x4){0.f, 0.f, 0.f, 0.f};

    const int srow = t >> 2, scol = (t & 3) * 8;

    for (int k0 = 0; k0 < CDIM; k0 += 32) {
        #pragma unroll
        for (int r = 0; r < 2; ++r)
            ASYNC_CP16(a + (size_t)(m0 + r * 64 + srow) * CDIM + k0 + scol,
                       a_s + (r * 64 + srow) * 32 + scol);
        #pragma unroll
        for (int r = 0; r < 2; ++r)
            ASYNC_CP16(bt + (size_t)(n0 + r * 64 + srow) * CDIM + k0 + scol,
                       b_s + (r * 64 + srow) * 32 + scol);
        __syncthreads();
        bf16x8 af[4], bfr[4];
        #pragma unroll
        for (int i = 0; i < 4; ++i)
            af[i] = *(const bf16x8*)(a_s + (wm + i * 16 + lm) * 32 + lq * 8);
        #pragma unroll
        for (int j = 0; j < 4; ++j)
            bfr[j] = *(const bf16x8*)(b_s + (wn + j * 16 + lm) * 32 + lq * 8);
        #pragma unroll
        for (int i = 0; i < 4; ++i)
            #pragma unroll
            for (int j = 0; j < 4; ++j)
                acc[i][j] = __builtin_amdgcn_mfma_f32_16x16x32_bf16(
                    af[i], bfr[j], acc[i][j], 0, 0, 0);
        __syncthreads();
    }

    if (OUT_BF16) {
        unsigned short* c = (unsigned short*)C + (size_t)z * M * NPIX;
        #pragma unroll
        for (int i = 0; i < 4; ++i)
            #pragma unroll
            for (int j = 0; j < 4; ++j) {
                size_t base = (size_t)(m0 + wm + i * 16 + lq * 4) * NPIX
                            + (n0 + wn + j * 16 + lm);
                #pragma unroll
                for (int r = 0; r < 4; ++r)
                    c[base + (size_t)r * NPIX] = f2bf(acc[i][j][r]);
            }
    } else {
        float* c = (float*)C + (size_t)z * M * NPIX;
        #pragma unroll
        for (int i = 0; i < 4; ++i)
            #pragma unroll
            for (int j = 0; j < 4; ++j) {
                size_t base = (size_t)(m0 + wm + i * 16 + lq * 4) * NPIX
                            + (n0 + wn + j * 16 + lm);
                #pragma unroll
                for (int r = 0; r < 4; ++r)
                    c[base + (size_t)r * NPIX] = acc[i][j][r];
            }
    }
}

// ------- helper: 10-wide bf16 window from an LDS row (vector b128 + edge scalars) -------
__device__ __forceinline__ void row10_bf(const unsigned short* row, int x0, float* a)
{
    u16x8 v = *(const u16x8*)(row + x0);
    a[0] = (x0 == 0) ? 0.f : bf2f(row[x0 - 1]);
    #pragma unroll
    for (int i = 0; i < 8; ++i) a[1 + i] = bf2f((unsigned short)v[i]);
    a[9] = (x0 == 120) ? 0.f : bf2f(row[x0 + 8]);
}

// ---------------- fast LDS-stripe depthwise 3x3 (bf16 -> bf16), fused q/k sum-of-squares ----
// grid (4 stripes, 1152 ch, z), 256 thr. Stripe = 32 output rows; LDS = 34 rows staged.
__global__ __launch_bounds__(256) void dwconv_fast_kernel(
    const unsigned short* __restrict__ X, const float* __restrict__ Wd,
    unsigned short* __restrict__ Y, float* __restrict__ norms2)
{
    const int z = blockIdx.z, c = blockIdx.y, s0 = blockIdx.x * 32;
    const int t = threadIdx.x;
    const unsigned short* xin = X + ((size_t)z * C3 + c) * NPIX;
    __shared__ unsigned short xs[34 * 136];   // rows s0-1 .. s0+32, stride 136 (16B-aligned, +4 bank shift)

    for (int g = t; g < 34 * 16; g += 256) {
        const int r = g >> 4, cg = (g & 15) << 3;
        const int y = s0 - 1 + r;
        u16x8 v = (u16x8)(short)0;
        if (y >= 0 && y < HH) v = *(const u16x8*)(xin + y * WW + cg);
        *(u16x8*)(xs + r * 136 + cg) = v;
    }
    __syncthreads();

    float w[9];
    #pragma unroll
    for (int i = 0; i < 9; ++i) w[i] = Wd[c * 9 + i];

    const int r0 = (t >> 4) * 2, x0 = (t & 15) * 8;
    const bool do_ss = (c < 2 * CDIM);
    float ss = 0.f;
    #pragma unroll
    for (int orow = 0; orow < 2; ++orow) {
        const int ry = r0 + orow;
        float a0[10], a1[10], a2[10];
        row10_bf(xs + (ry + 0) * 136, x0, a0);
        row10_bf(xs + (ry + 1) * 136, x0, a1);
        row10_bf(xs + (ry + 2) * 136, x0, a2);
        unsigned short ob[8];
        #pragma unroll
        for (int px = 0; px < 8; ++px) {
            float s = w[0] * a0[px] + w[1] * a0[px + 1] + w[2] * a0[px + 2]
                    + w[3] * a1[px] + w[4] * a1[px + 1] + w[5] * a1[px + 2]
                    + w[6] * a2[px] + w[7] * a2[px + 1] + w[8] * a2[px + 2];
            if (do_ss) ss += s * s;
            ob[px] = f2bf(s);
        }
        *(uint4*)(Y + ((size_t)z * C3 + c) * NPIX + (s0 + ry) * WW + x0) = *(uint4*)ob;
    }

    if (do_ss) {
        #pragma unroll
        for (int off = 32; off; off >>= 1) ss += __shfl_xor(ss, off, 64);
        __shared__ float red[4];
        if ((t & 63) == 0) red[t >> 6] = ss;
        __syncthreads();
        if (t == 0) {
            const int qk = c / CDIM, ch = c % CDIM;
            atomicAdd(&norms2[((size_t)z * 2 + qk) * CDIM + ch],
                      red[0] + red[1] + red[2] + red[3]);
        }
    }
}

// ---------------- fused pos branch: out += dw3x3(gelu(dw3x3(v))) ----------------
// grid (4 stripes, 384 ch, z), 256 thr. 32 output rows; t1 rows -1..32 in LDS fp32.
__global__ __launch_bounds__(256) void pos_fused_kernel(
    const unsigned short* __restrict__ QKdw, const float* __restrict__ W1,
    const float* __restrict__ W2, float* __restrict__ Out)
{
    const int z = blockIdx.z, c = blockIdx.y, s0 = blockIdx.x * 32;
    const int t = threadIdx.x;
    const unsigned short* vin = QKdw + ((size_t)z * C3 + 2 * CDIM + c) * NPIX;
    __shared__ unsigned short vs[36 * 136];  // image rows s0-2 .. s0+33
    __shared__ float ts[34 * 132];           // t1 rows s0-1 .. s0+32, stride 132 (16B-aligned, +4 bank shift)

    for (int g = t; g < 36 * 16; g += 256) {
        const int r = g >> 4, cg = (g & 15) << 3;
        const int y = s0 - 2 + r;
        u16x8 v = (u16x8)(short)0;
        if (y >= 0 && y < HH) v = *(const u16x8*)(vin + y * WW + cg);
        *(u16x8*)(vs + r * 136 + cg) = v;
    }
    __syncthreads();

    float w1[9], w2[9];
    #pragma unroll
    for (int i = 0; i < 9; ++i) { w1[i] = W1[c * 9 + i]; w2[i] = W2[c * 9 + i]; }

    const int r0 = (t >> 4) * 2, x0 = (t & 15) * 8;

    // t1 main rows (tr = 1 + r0 + {0,1}, covering tr 1..32)
    #pragma unroll
    for (int orow = 0; orow < 2; ++orow) {
        const int tr = 1 + r0 + orow;            // t1 LDS row; image row s0-1+tr in-range
        float a0[10], a1[10], a2[10];
        row10_bf(vs + (tr + 0) * 136, x0, a0);
        row10_bf(vs + (tr + 1) * 136, x0, a1);
        row10_bf(vs + (tr + 2) * 136, x0, a2);
        #pragma unroll
        for (int px = 0; px < 8; ++px) {
            float s = w1[0] * a0[px] + w1[1] * a0[px + 1] + w1[2] * a0[px + 2]
                    + w1[3] * a1[px] + w1[4] * a1[px + 1] + w1[5] * a1[px + 2]
                    + w1[6] * a2[px] + w1[7] * a2[px + 1] + w1[8] * a2[px + 2];
            ts[tr * 132 + x0 + px] = 0.5f * s * (1.0f + erff(s * 0.70710678118654752f));
        }
    }
    // t1 halo rows tr=0 and tr=33 (threads 0..31), zero outside the image
    if (t < 32) {
        const int tr = (t >> 4) ? 33 : 0;
        const int xh = (t & 15) * 8;
        const int yt = s0 - 1 + tr;
        if (yt < 0 || yt >= HH) {
            #pragma unroll
            for (int px = 0; px < 8; ++px) ts[tr * 132 + xh + px] = 0.f;
        } else {
            float a0[10], a1[10], a2[10];
            row10_bf(vs + (tr + 0) * 136, xh, a0);
            row10_bf(vs + (tr + 1) * 136, xh, a1);
            row10_bf(vs + (tr + 2) * 136, xh, a2);
            #pragma unroll
            for (int px = 0; px < 8; ++px) {
                float s = w1[0] * a0[px] + w1[1] * a0[px + 1] + w1[2] * a0[px + 2]
                        + w1[3] * a1[px] + w1[4] * a1[px + 1] + w1[5] * a1[px + 2]
                        + w1[6] * a2[px] + w1[7] * a2[px + 1] + w1[8] * a2[px + 2];
                ts[tr * 132 + xh + px] = 0.5f * s * (1.0f + erff(s * 0.70710678118654752f));
            }
        }
    }
    __syncthreads();

    float* ob = Out + ((size_t)z * CDIM + c) * NPIX;
    #pragma unroll
    for (int orow = 0; orow < 2; ++orow) {
        const int o = r0 + orow;                 // output row within stripe
        float b0[10], b1[10], b2[10];
        #pragma unroll
        for (int rr = 0; rr < 3; ++rr) {
            float* dst = (rr == 0) ? b0 : (rr == 1) ? b1 : b2;
            const float* trow = ts + (o + rr) * 132;
            float4 v0 = *(const float4*)(trow + x0);
            float4 v1 = *(const float4*)(trow + x0 + 4);
            dst[0] = (x0 == 0) ? 0.f : trow[x0 - 1];
            dst[1] = v0.x; dst[2] = v0.y; dst[3] = v0.z; dst[4] = v0.w;
            dst[5] = v1.x; dst[6] = v1.y; dst[7] = v1.z; dst[8] = v1.w;
            dst[9] = (x0 == 120) ? 0.f : trow[x0 + 8];
        }
        float res[8];
        #pragma unroll
        for (int px = 0; px < 8; ++px)
            res[px] = w2[0] * b0[px] + w2[1] * b0[px + 1] + w2[2] * b0[px + 2]
                    + w2[3] * b1[px] + w2[4] * b1[px + 1] + w2[5] * b1[px + 2]
                    + w2[6] * b2[px] + w2[7] * b2[px + 1] + w2[8] * b2[px + 2];
        float* op = ob + (s0 + o) * WW + x0;
        float4 c0 = *(const float4*)op, c1 = *(const float4*)(op + 4);
        c0.x += res[0]; c0.y += res[1]; c0.z += res[2]; c0.w += res[3];
        c1.x += res[4]; c1.y += res[5]; c1.z += res[6]; c1.w += res[7];
        *(float4*)op = c0; *(float4*)(op + 4) = c1;
    }
}

// ---------------- scores via MFMA, fragments straight from global (K-contiguous) ----------
__global__ __launch_bounds__(256) void scores_mfma_kernel(
    const unsigned short* __restrict__ QKdw, float* __restrict__ S)
{
    const int z = blockIdx.z, h = blockIdx.y, chunk = blockIdx.x;
    const unsigned short* qb = QKdw + ((size_t)z * C3 + h * CPH) * NPIX;
    const unsigned short* kb = qb + (size_t)CDIM * NPIX;
    const int t = threadIdx.x, wave = t >> 6, lane = t & 63;
    const int lm = lane & 15, lq = lane >> 4;
    const int kw0 = chunk * 2048 + wave * 512;

    f32x4 acc[3][3];
    #pragma unroll
    for (int i = 0; i < 3; ++i)
        #pragma unroll
        for (int j = 0; j < 3; ++j)
            acc[i][j] = (f32x4){0.f, 0.f, 0.f, 0.f};

    for (int ks = 0; ks < 512; ks += 32) {
        const int kk = kw0 + ks + lq * 8;
        bf16x8 af[3], bfr[3];
        #pragma unroll
        for (int i = 0; i < 3; ++i)
            af[i] = *(const bf16x8*)(qb + (size_t)(i * 16 + lm) * NPIX + kk);
        #pragma unroll
        for (int j = 0; j < 3; ++j)
            bfr[j] = *(const bf16x8*)(kb + (size_t)(j * 16 + lm) * NPIX + kk);
        #pragma unroll
        for (int i = 0; i < 3; ++i)
            #pragma unroll
            for (int j = 0; j < 3; ++j)
                acc[i][j] = __builtin_amdgcn_mfma_f32_16x16x32_bf16(
                    af[i], bfr[j], acc[i][j], 0, 0, 0);
    }
    __shared__ float s_red[CPH * CPH];
    for (int e = t; e < CPH * CPH; e += 256) s_red[e] = 0.f;
    __syncthreads();
    #pragma unroll
    for (int i = 0; i < 3; ++i)
        #pragma unroll
        for (int j = 0; j < 3; ++j)
            #pragma unroll
            for (int r = 0; r < 4; ++r)
                atomicAdd(&s_red[(i * 16 + lq * 4 + r) * CPH + j * 16 + lm], acc[i][j][r]);
    __syncthreads();
    float* Sb = S + (size_t)(z * NHEADS + h) * CPH * CPH;
    for (int e = t; e < CPH * CPH; e += 256) atomicAdd(&Sb[e], s_red[e]);
}

// ---------------- dual softmax blend (in-place on S); norms2 holds SUM OF SQUARES ---------
__global__ __launch_bounds__(64) void softmax_kernel(
    float* __restrict__ S, const float* __restrict__ norms2,
    const int* __restrict__ mask, const float* __restrict__ temp,
    const float* __restrict__ wblend)
{
    const int z = blockIdx.z, h = blockIdx.y, c = blockIdx.x;
    const int d = threadIdx.x;
    float* Srow = S + ((size_t)(z * NHEADS + h) * CPH + c) * CPH;
    const float nq = fmaxf(sqrtf(norms2[((size_t)z * 2 + 0) * CDIM + h * CPH + c]), 1e-12f);
    float a0 = -INFINITY, a1 = -INFINITY;
    if (d < CPH) {
        const float nk = fmaxf(sqrtf(norms2[((size_t)z * 2 + 1) * CDIM + h * CPH + d]), 1e-12f);
        a0 = Srow[d] / (nq * nk) * temp[h];
        a1 = (mask[(h * CPH + c) * CPH + d] == 0) ? -1e9f : a0;
    }
    float m0 = a0, m1 = a1;
    #pragma unroll
    for (int off = 32; off; off >>= 1) {
        m0 = fmaxf(m0, __shfl_xor(m0, off, 64));
        m1 = fmaxf(m1, __shfl_xor(m1, off, 64));
    }
    float e0 = (d < CPH) ? expf(a0 - m0) : 0.f;
    float e1 = (d < CPH) ? expf(a1 - m1) : 0.f;
    float s0 = e0, s1 = e1;
    #pragma unroll
    for (int off = 32; off; off >>= 1) {
        s0 += __shfl_xor(s0, off, 64);
        s1 += __shfl_xor(s1, off, 64);
    }
    const float b0 = wblend[0], b1 = wblend[1];
    const float bm = fmaxf(b0, b1);
    const float eb0 = expf(b0 - bm), eb1 = expf(b1 - bm);
    const float ws0 = eb0 / (eb0 + eb1), ws1 = eb1 / (eb0 + eb1);
    if (d < CPH) Srow[d] = (e0 / s0) * ws0 + (e1 / s1) * ws1;
}

// ---------------- Mcat[z][:, h*48+d] = P[:, h*48+c] @ A_h[c][d] ----------------
__global__ __launch_bounds__(256) void mproj_kernel(
    const float* __restrict__ S, const float* __restrict__ P,
    unsigned short* __restrict__ Mcat)
{
    const int z = blockIdx.y, h = blockIdx.x;
    __shared__ float As[CPH * CPH];
    const float* Sb = S + (size_t)(z * NHEADS + h) * CPH * CPH;
    for (int e = threadIdx.x; e < CPH * CPH; e += 256) As[e] = Sb[e];
    __syncthreads();
    unsigned short* Mz = Mcat + (size_t)z * CDIM * CDIM;
    for (int e = threadIdx.x; e < CDIM * CPH; e += 256) {
        const int m = e / CPH, d = e % CPH;
        const float* pr = P + (size_t)m * CDIM + h * CPH;
        float s = 0.f;
        #pragma unroll
        for (int c = 0; c < CPH; ++c) s = fmaf(pr[c], As[c * CPH + d], s);
        Mz[(size_t)m * CDIM + h * CPH + d] = f2bf(s);
    }
}

extern "C" void kernel_launch(void* const* d_in, const int* in_sizes, int n_in,
                              void* d_out, int out_size, void* d_ws, size_t ws_size,
                              hipStream_t stream)
{
    const float* x      = (const float*)d_in[0];
    const int*   mask   = (const int*)d_in[1];
    const float* qkv_w  = (const float*)d_in[2];
    const float* dw_w   = (const float*)d_in[3];
    const float* proj_w = (const float*)d_in[4];
    const float* temp   = (const float*)d_in[5];
    const float* wblend = (const float*)d_in[6];
    const float* pos_w1 = (const float*)d_in[7];
    const float* pos_w2 = (const float*)d_in[8];
    float* out = (float*)d_out;

    auto need = [](size_t nb) {
        return nb * ((size_t)NPIX * CDIM * 2
                   + (size_t)C3 * NPIX * 2
                   + (size_t)C3 * NPIX * 2
                   + (size_t)NHEADS * CPH * CPH * 4
                   + (size_t)2 * CDIM * 4
                   + (size_t)CDIM * CDIM * 2)
             + (size_t)C3 * CDIM * 2;
    };
    int nb = 4;
    if (need(4) > ws_size) nb = (need(2) <= ws_size) ? 2 : 1;

    char* p = (char*)d_ws;
    unsigned short* w_bf  = (unsigned short*)p; p += (size_t)C3 * CDIM * 2;
    unsigned short* x_t   = (unsigned short*)p; p += (size_t)nb * NPIX * CDIM * 2;
    unsigned short* qkv0  = (unsigned short*)p; p += (size_t)nb * C3 * NPIX * 2;
    unsigned short* qkvdw = (unsigned short*)p; p += (size_t)nb * C3 * NPIX * 2;
    float* S      = (float*)p; p += (size_t)nb * NHEADS * CPH * CPH * 4;
    float* norms2 = (float*)p; p += (size_t)nb * 2 * CDIM * 4;
    unsigned short* Mcat = (unsigned short*)p;
    unsigned short* v_t = qkv0;                                  // alias: qkv0 dead by then

    cast_bf16_kernel<<<dim3(C3 * CDIM / 4 / 256), 256, 0, stream>>>(qkv_w, w_bf, C3 * CDIM / 4);

    for (int b0 = 0; b0 < 4; b0 += nb) {
        const float* xb = x + (size_t)b0 * CDIM * NPIX;
        float* outb = out + (size_t)b0 * CDIM * NPIX;

        hipMemsetAsync(S, 0, (size_t)nb * NHEADS * CPH * CPH * 4, stream);
        hipMemsetAsync(norms2, 0, (size_t)nb * 2 * CDIM * 4, stream);

        // x -> bf16 x^T [n][k]
        transpose_kernel<0><<<dim3(NPIX / 64, CDIM / 64, nb), 256, 0, stream>>>(
            xb, x_t, (size_t)CDIM * NPIX);
        // qkv 1x1 conv: bf16 MFMA GEMM -> qkv0 bf16
        mfma_gemm_kernel<1, 0><<<dim3(NPIX / 128, C3 / 128, nb), 256, 0, stream>>>(
            w_bf, x_t, qkv0, C3);
        // depthwise 3x3 on all 1152 ch (LDS stripes) + fused q/k sum-of-squares
        dwconv_fast_kernel<<<dim3(4, C3, nb), 256, 0, stream>>>(
            qkv0, dw_w, qkvdw, norms2);
        // raw scores
        scores_mfma_kernel<<<dim3(8, NHEADS, nb), 256, 0, stream>>>(qkvdw, S);
        // dual-softmax blend
        softmax_kernel<<<dim3(CPH, NHEADS, nb), 64, 0, stream>>>(
            S, norms2, mask, temp, wblend);
        // fold proj into attn: Mcat = [P_h @ A_h]
        mproj_kernel<<<dim3(NHEADS, nb), 256, 0, stream>>>(S, proj_w, Mcat);
        // v -> bf16 v^T [n][k]
        transpose_kernel<1><<<dim3(NPIX / 64, CDIM / 64, nb), 256, 0, stream>>>(
            qkvdw + (size_t)2 * CDIM * NPIX, v_t, (size_t)C3 * NPIX);
        // fused attn@v + proj: out = Mcat @ v^T  (fp32, direct to d_out)
        mfma_gemm_kernel<0, 1><<<dim3(NPIX / 128, CDIM / 128, nb), 256, 0, stream>>>(
            Mcat, v_t, outb, CDIM);
        // fused pos branch: out += dw3x3(gelu(dw3x3(v)))
        pos_fused_kernel<<<dim3(4, CDIM, nb), 256, 0, stream>>>(
            qkvdw, pos_w1, pos_w2, outb);
    }
}

// Round 4
// 571.177 us; speedup vs baseline: 3.9005x; 1.0081x over previous
//
#include <hip/hip_runtime.h>
#include <math.h>

#define CDIM 384
#define C3   1152
#define HH   128
#define WW   128
#define NPIX 16384
#define NHEADS 8
#define CPH  48

typedef short bf16x8 __attribute__((ext_vector_type(8)));
typedef float f32x4  __attribute__((ext_vector_type(4)));
typedef unsigned short u16x8 __attribute__((ext_vector_type(8)));
typedef _Float16 f16x8 __attribute__((ext_vector_type(8)));

__device__ __forceinline__ float bf2f(unsigned short h) {
    union { unsigned u; float f; } x; x.u = ((unsigned)h) << 16; return x.f;
}
__device__ __forceinline__ unsigned short f2bf(float f) {
    union { float f; unsigned u; } x; x.f = f;
    unsigned r = x.u + 0x7fffu + ((x.u >> 16) & 1u);
    return (unsigned short)(r >> 16);
}

#define ASYNC_CP16(gp, lp) \
    __builtin_amdgcn_global_load_lds( \
        (const __attribute__((address_space(1))) unsigned int*)(gp), \
        (__attribute__((address_space(3))) unsigned int*)(lp), 16, 0, 0)

// ---------------- fp32 -> bf16 elementwise cast (weights) ----------------
__global__ __launch_bounds__(256) void cast_bf16_kernel(
    const float* __restrict__ in, unsigned short* __restrict__ out, int n4)
{
    int i = blockIdx.x * 256 + threadIdx.x;
    if (i < n4) {
        float4 v = *(const float4*)(in + (size_t)i * 4);
        ushort4 o = { f2bf(v.x), f2bf(v.y), f2bf(v.z), f2bf(v.w) };
        *(ushort4*)(out + (size_t)i * 4) = o;
    }
}

// ---------------- transpose [K=384][NPIX] -> bf16 [NPIX][384] ----------------
template<int IN_BF16>
__global__ __launch_bounds__(256) void transpose_kernel(
    const void* __restrict__ in_, unsigned short* __restrict__ out, size_t in_zstride)
{
    const int z = blockIdx.z;
    const int n0 = blockIdx.x * 64, k0 = blockIdx.y * 64;
    __shared__ unsigned short tile[64][69];
    const int t = threadIdx.x;
    if (IN_BF16) {
        const unsigned short* in = (const unsigned short*)in_ + (size_t)z * in_zstride;
        #pragma unroll
        for (int r = 0; r < 4; ++r) {
            int kk = r * 16 + (t >> 4), nn = (t & 15) * 4;
            ushort4 v = *(const ushort4*)(in + (size_t)(k0 + kk) * NPIX + n0 + nn);
            tile[kk][nn] = v.x; tile[kk][nn + 1] = v.y;
            tile[kk][nn + 2] = v.z; tile[kk][nn + 3] = v.w;
        }
    } else {
        const float* in = (const float*)in_ + (size_t)z * in_zstride;
        #pragma unroll
        for (int r = 0; r < 4; ++r) {
            int kk = r * 16 + (t >> 4), nn = (t & 15) * 4;
            float4 v = *(const float4*)(in + (size_t)(k0 + kk) * NPIX + n0 + nn);
            tile[kk][nn] = f2bf(v.x); tile[kk][nn + 1] = f2bf(v.y);
            tile[kk][nn + 2] = f2bf(v.z); tile[kk][nn + 3] = f2bf(v.w);
        }
    }
    __syncthreads();
    unsigned short* o = out + (size_t)z * NPIX * CDIM;
    #pragma unroll
    for (int r = 0; r < 2; ++r) {
        int nn = r * 32 + (t >> 3), kk = (t & 7) * 8;
        ushort4 a, b;
        a.x = tile[kk + 0][nn]; a.y = tile[kk + 1][nn];
        a.z = tile[kk + 2][nn]; a.w = tile[kk + 3][nn];
        b.x = tile[kk + 4][nn]; b.y = tile[kk + 5][nn];
        b.z = tile[kk + 6][nn]; b.w = tile[kk + 7][nn];
        *(ushort4*)(o + (size_t)(n0 + nn) * CDIM + k0 + kk) = a;
        *(ushort4*)(o + (size_t)(n0 + nn) * CDIM + k0 + kk + 4) = b;
    }
}

// ---------------- bf16 MFMA GEMM: C[z][m][n] = sum_k A[m][k] * Bt[z][n][k] ----------------
// XOR-swizzled LDS: slot (row m, 16B-chunk kb) holds global chunk kb ^ ((m>>1)&3).
// Staging swizzles the GLOBAL address (DMA LDS dest is frozen at base+lane*16);
// fragment reads apply lq ^ ((lm>>1)&3) -> 2-way bank aliasing (free, m136).
// OUT_MODE: 0 = fp32, 1 = bf16, 2 = fp16
template<int OUT_MODE, int A_PER_Z>
__global__ __launch_bounds__(256) void mfma_gemm_kernel(
    const unsigned short* __restrict__ A, const unsigned short* __restrict__ Bt,
    void* __restrict__ C, int M)
{
    const int z = blockIdx.z;
    const int n0 = blockIdx.x * 128;
    const int m0 = blockIdx.y * 128;
    const unsigned short* a = A + (A_PER_Z ? (size_t)z * M * CDIM : 0);
    const unsigned short* bt = Bt + (size_t)z * NPIX * CDIM;
    const int t = threadIdx.x;
    const int wave = t >> 6, lane = t & 63;
    const int wm = (wave & 1) * 64, wn = (wave >> 1) * 64;
    const int lm = lane & 15, lq = lane >> 4;

    __shared__ unsigned short a_s[128 * 32];
    __shared__ unsigned short b_s[128 * 32];

    f32x4 acc[4][4];
    #pragma unroll
    for (int i = 0; i < 4; ++i)
        #pragma unroll
        for (int j = 0; j < 4; ++j)
            acc[i][j] = (f32x4){0.f, 0.f, 0.f, 0.f};

    const int srow = t >> 2;
    const int kbs  = ((t & 3) ^ ((t >> 3) & 3)) * 8;   // swizzled source k-offset (elems)
    const int sdst = (t & 3) * 8;                       // dense LDS dest (elems)
    const int rsw  = ((lm >> 1) & 3);                   // read-side swizzle base

    for (int k0 = 0; k0 < CDIM; k0 += 32) {
        #pragma unroll
        for (int r = 0; r < 2; ++r)
            ASYNC_CP16(a + (size_t)(m0 + r * 64 + srow) * CDIM + k0 + kbs,
                       a_s + (r * 64 + srow) * 32 + sdst);
        #pragma unroll
        for (int r = 0; r < 2; ++r)
            ASYNC_CP16(bt + (size_t)(n0 + r * 64 + srow) * CDIM + k0 + kbs,
                       b_s + (r * 64 + srow) * 32 + sdst);
        __syncthreads();
        bf16x8 af[4], bfr[4];
        const int ko = (lq ^ rsw) * 8;
        #pragma unroll
        for (int i = 0; i < 4; ++i)
            af[i] = *(const bf16x8*)(a_s + (wm + i * 16 + lm) * 32 + ko);
        #pragma unroll
        for (int j = 0; j < 4; ++j)
            bfr[j] = *(const bf16x8*)(b_s + (wn + j * 16 + lm) * 32 + ko);
        #pragma unroll
        for (int i = 0; i < 4; ++i)
            #pragma unroll
            for (int j = 0; j < 4; ++j)
                acc[i][j] = __builtin_amdgcn_mfma_f32_16x16x32_bf16(
                    af[i], bfr[j], acc[i][j], 0, 0, 0);
        __syncthreads();
    }

    if (OUT_MODE == 1) {
        unsigned short* c = (unsigned short*)C + (size_t)z * M * NPIX;
        #pragma unroll
        for (int i = 0; i < 4; ++i)
            #pragma unroll
            for (int j = 0; j < 4; ++j) {
                size_t base = (size_t)(m0 + wm + i * 16 + lq * 4) * NPIX
                            + (n0 + wn + j * 16 + lm);
                #pragma unroll
                for (int r = 0; r < 4; ++r)
                    c[base + (size_t)r * NPIX] = f2bf(acc[i][j][r]);
            }
    } else if (OUT_MODE == 2) {
        _Float16* c = (_Float16*)C + (size_t)z * M * NPIX;
        #pragma unroll
        for (int i = 0; i < 4; ++i)
            #pragma unroll
            for (int j = 0; j < 4; ++j) {
                size_t base = (size_t)(m0 + wm + i * 16 + lq * 4) * NPIX
                            + (n0 + wn + j * 16 + lm);
                #pragma unroll
                for (int r = 0; r < 4; ++r)
                    c[base + (size_t)r * NPIX] = (_Float16)acc[i][j][r];
            }
    } else {
        float* c = (float*)C + (size_t)z * M * NPIX;
        #pragma unroll
        for (int i = 0; i < 4; ++i)
            #pragma unroll
            for (int j = 0; j < 4; ++j) {
                size_t base = (size_t)(m0 + wm + i * 16 + lq * 4) * NPIX
                            + (n0 + wn + j * 16 + lm);
                #pragma unroll
                for (int r = 0; r < 4; ++r)
                    c[base + (size_t)r * NPIX] = acc[i][j][r];
            }
    }
}

// ------- helper: 10-wide bf16 window from an LDS row (vector b128 + edge scalars) -------
__device__ __forceinline__ void row10_bf(const unsigned short* row, int x0, float* a)
{
    u16x8 v = *(const u16x8*)(row + x0);
    a[0] = (x0 == 0) ? 0.f : bf2f(row[x0 - 1]);
    #pragma unroll
    for (int i = 0; i < 8; ++i) a[1 + i] = bf2f((unsigned short)v[i]);
    a[9] = (x0 == 120) ? 0.f : bf2f(row[x0 + 8]);
}

// ---------------- fast LDS-stripe depthwise 3x3 (bf16 -> bf16), fused q/k sum-of-squares ----
__global__ __launch_bounds__(256) void dwconv_fast_kernel(
    const unsigned short* __restrict__ X, const float* __restrict__ Wd,
    unsigned short* __restrict__ Y, float* __restrict__ norms2)
{
    const int z = blockIdx.z, c = blockIdx.y, s0 = blockIdx.x * 32;
    const int t = threadIdx.x;
    const unsigned short* xin = X + ((size_t)z * C3 + c) * NPIX;
    __shared__ unsigned short xs[34 * 136];

    for (int g = t; g < 34 * 16; g += 256) {
        const int r = g >> 4, cg = (g & 15) << 3;
        const int y = s0 - 1 + r;
        u16x8 v = (u16x8)(short)0;
        if (y >= 0 && y < HH) v = *(const u16x8*)(xin + y * WW + cg);
        *(u16x8*)(xs + r * 136 + cg) = v;
    }
    __syncthreads();

    float w[9];
    #pragma unroll
    for (int i = 0; i < 9; ++i) w[i] = Wd[c * 9 + i];

    const int r0 = (t >> 4) * 2, x0 = (t & 15) * 8;
    const bool do_ss = (c < 2 * CDIM);
    float ss = 0.f;
    #pragma unroll
    for (int orow = 0; orow < 2; ++orow) {
        const int ry = r0 + orow;
        float a0[10], a1[10], a2[10];
        row10_bf(xs + (ry + 0) * 136, x0, a0);
        row10_bf(xs + (ry + 1) * 136, x0, a1);
        row10_bf(xs + (ry + 2) * 136, x0, a2);
        unsigned short ob[8];
        #pragma unroll
        for (int px = 0; px < 8; ++px) {
            float s = w[0] * a0[px] + w[1] * a0[px + 1] + w[2] * a0[px + 2]
                    + w[3] * a1[px] + w[4] * a1[px + 1] + w[5] * a1[px + 2]
                    + w[6] * a2[px] + w[7] * a2[px + 1] + w[8] * a2[px + 2];
            if (do_ss) ss += s * s;
            ob[px] = f2bf(s);
        }
        *(uint4*)(Y + ((size_t)z * C3 + c) * NPIX + (s0 + ry) * WW + x0) = *(uint4*)ob;
    }

    if (do_ss) {
        #pragma unroll
        for (int off = 32; off; off >>= 1) ss += __shfl_xor(ss, off, 64);
        __shared__ float red[4];
        if ((t & 63) == 0) red[t >> 6] = ss;
        __syncthreads();
        if (t == 0) {
            const int qk = c / CDIM, ch = c % CDIM;
            atomicAdd(&norms2[((size_t)z * 2 + qk) * CDIM + ch],
                      red[0] + red[1] + red[2] + red[3]);
        }
    }
}

// ---------------- fused pos branch + final combine: out = attn(fp16) + dw(gelu(dw(v))) -----
__global__ __launch_bounds__(256) void pos_fused_kernel(
    const unsigned short* __restrict__ QKdw, const _Float16* __restrict__ Attn,
    const float* __restrict__ W1, const float* __restrict__ W2,
    float* __restrict__ Out)
{
    const int z = blockIdx.z, c = blockIdx.y, s0 = blockIdx.x * 32;
    const int t = threadIdx.x;
    const unsigned short* vin = QKdw + ((size_t)z * C3 + 2 * CDIM + c) * NPIX;
    __shared__ unsigned short vs[36 * 136];
    __shared__ float ts[34 * 132];

    for (int g = t; g < 36 * 16; g += 256) {
        const int r = g >> 4, cg = (g & 15) << 3;
        const int y = s0 - 2 + r;
        u16x8 v = (u16x8)(short)0;
        if (y >= 0 && y < HH) v = *(const u16x8*)(vin + y * WW + cg);
        *(u16x8*)(vs + r * 136 + cg) = v;
    }
    __syncthreads();

    float w1[9], w2[9];
    #pragma unroll
    for (int i = 0; i < 9; ++i) { w1[i] = W1[c * 9 + i]; w2[i] = W2[c * 9 + i]; }

    const int r0 = (t >> 4) * 2, x0 = (t & 15) * 8;

    #pragma unroll
    for (int orow = 0; orow < 2; ++orow) {
        const int tr = 1 + r0 + orow;
        float a0[10], a1[10], a2[10];
        row10_bf(vs + (tr + 0) * 136, x0, a0);
        row10_bf(vs + (tr + 1) * 136, x0, a1);
        row10_bf(vs + (tr + 2) * 136, x0, a2);
        #pragma unroll
        for (int px = 0; px < 8; ++px) {
            float s = w1[0] * a0[px] + w1[1] * a0[px + 1] + w1[2] * a0[px + 2]
                    + w1[3] * a1[px] + w1[4] * a1[px + 1] + w1[5] * a1[px + 2]
                    + w1[6] * a2[px] + w1[7] * a2[px + 1] + w1[8] * a2[px + 2];
            ts[tr * 132 + x0 + px] = 0.5f * s * (1.0f + erff(s * 0.70710678118654752f));
        }
    }
    if (t < 32) {
        const int tr = (t >> 4) ? 33 : 0;
        const int xh = (t & 15) * 8;
        const int yt = s0 - 1 + tr;
        if (yt < 0 || yt >= HH) {
            #pragma unroll
            for (int px = 0; px < 8; ++px) ts[tr * 132 + xh + px] = 0.f;
        } else {
            float a0[10], a1[10], a2[10];
            row10_bf(vs + (tr + 0) * 136, xh, a0);
            row10_bf(vs + (tr + 1) * 136, xh, a1);
            row10_bf(vs + (tr + 2) * 136, xh, a2);
            #pragma unroll
            for (int px = 0; px < 8; ++px) {
                float s = w1[0] * a0[px] + w1[1] * a0[px + 1] + w1[2] * a0[px + 2]
                        + w1[3] * a1[px] + w1[4] * a1[px + 1] + w1[5] * a1[px + 2]
                        + w1[6] * a2[px] + w1[7] * a2[px + 1] + w1[8] * a2[px + 2];
                ts[tr * 132 + xh + px] = 0.5f * s * (1.0f + erff(s * 0.70710678118654752f));
            }
        }
    }
    __syncthreads();

    float* ob = Out + ((size_t)z * CDIM + c) * NPIX;
    const _Float16* ab = Attn + ((size_t)z * CDIM + c) * NPIX;
    #pragma unroll
    for (int orow = 0; orow < 2; ++orow) {
        const int o = r0 + orow;
        float b0[10], b1[10], b2[10];
        #pragma unroll
        for (int rr = 0; rr < 3; ++rr) {
            float* dst = (rr == 0) ? b0 : (rr == 1) ? b1 : b2;
            const float* trow = ts + (o + rr) * 132;
            float4 v0 = *(const float4*)(trow + x0);
            float4 v1 = *(const float4*)(trow + x0 + 4);
            dst[0] = (x0 == 0) ? 0.f : trow[x0 - 1];
            dst[1] = v0.x; dst[2] = v0.y; dst[3] = v0.z; dst[4] = v0.w;
            dst[5] = v1.x; dst[6] = v1.y; dst[7] = v1.z; dst[8] = v1.w;
            dst[9] = (x0 == 120) ? 0.f : trow[x0 + 8];
        }
        f16x8 av = *(const f16x8*)(ab + (s0 + o) * WW + x0);
        float res[8];
        #pragma unroll
        for (int px = 0; px < 8; ++px)
            res[px] = (float)av[px]
                    + w2[0] * b0[px] + w2[1] * b0[px + 1] + w2[2] * b0[px + 2]
                    + w2[3] * b1[px] + w2[4] * b1[px + 1] + w2[5] * b1[px + 2]
                    + w2[6] * b2[px] + w2[7] * b2[px + 1] + w2[8] * b2[px + 2];
        float* op = ob + (s0 + o) * WW + x0;
        *(float4*)op = make_float4(res[0], res[1], res[2], res[3]);
        *(float4*)(op + 4) = make_float4(res[4], res[5], res[6], res[7]);
    }
}

// ---------------- scores via MFMA, fragments straight from global (K-contiguous) ----------
__global__ __launch_bounds__(256) void scores_mfma_kernel(
    const unsigned short* __restrict__ QKdw, float* __restrict__ S)
{
    const int z = blockIdx.z, h = blockIdx.y, chunk = blockIdx.x;
    const unsigned short* qb = QKdw + ((size_t)z * C3 + h * CPH) * NPIX;
    const unsigned short* kb = qb + (size_t)CDIM * NPIX;
    const int t = threadIdx.x, wave = t >> 6, lane = t & 63;
    const int lm = lane & 15, lq = lane >> 4;
    const int kw0 = chunk * 2048 + wave * 512;

    f32x4 acc[3][3];
    #pragma unroll
    for (int i = 0; i < 3; ++i)
        #pragma unroll
        for (int j = 0; j < 3; ++j)
            acc[i][j] = (f32x4){0.f, 0.f, 0.f, 0.f};

    for (int ks = 0; ks < 512; ks += 32) {
        const int kk = kw0 + ks + lq * 8;
        bf16x8 af[3], bfr[3];
        #pragma unroll
        for (int i = 0; i < 3; ++i)
            af[i] = *(const bf16x8*)(qb + (size_t)(i * 16 + lm) * NPIX + kk);
        #pragma unroll
        for (int j = 0; j < 3; ++j)
            bfr[j] = *(const bf16x8*)(kb + (size_t)(j * 16 + lm) * NPIX + kk);
        #pragma unroll
        for (int i = 0; i < 3; ++i)
            #pragma unroll
            for (int j = 0; j < 3; ++j)
                acc[i][j] = __builtin_amdgcn_mfma_f32_16x16x32_bf16(
                    af[i], bfr[j], acc[i][j], 0, 0, 0);
    }
    __shared__ float s_red[CPH * CPH];
    for (int e = t; e < CPH * CPH; e += 256) s_red[e] = 0.f;
    __syncthreads();
    #pragma unroll
    for (int i = 0; i < 3; ++i)
        #pragma unroll
        for (int j = 0; j < 3; ++j)
            #pragma unroll
            for (int r = 0; r < 4; ++r)
                atomicAdd(&s_red[(i * 16 + lq * 4 + r) * CPH + j * 16 + lm], acc[i][j][r]);
    __syncthreads();
    float* Sb = S + (size_t)(z * NHEADS + h) * CPH * CPH;
    for (int e = t; e < CPH * CPH; e += 256) atomicAdd(&Sb[e], s_red[e]);
}

// ---------------- dual softmax blend (in-place on S); norms2 holds SUM OF SQUARES ---------
__global__ __launch_bounds__(64) void softmax_kernel(
    float* __restrict__ S, const float* __restrict__ norms2,
    const int* __restrict__ mask, const float* __restrict__ temp,
    const float* __restrict__ wblend)
{
    const int z = blockIdx.z, h = blockIdx.y, c = blockIdx.x;
    const int d = threadIdx.x;
    float* Srow = S + ((size_t)(z * NHEADS + h) * CPH + c) * CPH;
    const float nq = fmaxf(sqrtf(norms2[((size_t)z * 2 + 0) * CDIM + h * CPH + c]), 1e-12f);
    float a0 = -INFINITY, a1 = -INFINITY;
    if (d < CPH) {
        const float nk = fmaxf(sqrtf(norms2[((size_t)z * 2 + 1) * CDIM + h * CPH + d]), 1e-12f);
        a0 = Srow[d] / (nq * nk) * temp[h];
        a1 = (mask[(h * CPH + c) * CPH + d] == 0) ? -1e9f : a0;
    }
    float m0 = a0, m1 = a1;
    #pragma unroll
    for (int off = 32; off; off >>= 1) {
        m0 = fmaxf(m0, __shfl_xor(m0, off, 64));
        m1 = fmaxf(m1, __shfl_xor(m1, off, 64));
    }
    float e0 = (d < CPH) ? expf(a0 - m0) : 0.f;
    float e1 = (d < CPH) ? expf(a1 - m1) : 0.f;
    float s0 = e0, s1 = e1;
    #pragma unroll
    for (int off = 32; off; off >>= 1) {
        s0 += __shfl_xor(s0, off, 64);
        s1 += __shfl_xor(s1, off, 64);
    }
    const float b0 = wblend[0], b1 = wblend[1];
    const float bm = fmaxf(b0, b1);
    const float eb0 = expf(b0 - bm), eb1 = expf(b1 - bm);
    const float ws0 = eb0 / (eb0 + eb1), ws1 = eb1 / (eb0 + eb1);
    if (d < CPH) Srow[d] = (e0 / s0) * ws0 + (e1 / s1) * ws1;
}

// ---------------- Mcat[z][:, h*48+d] = P[:, h*48+c] @ A_h[c][d] ----------------
__global__ __launch_bounds__(256) void mproj_kernel(
    const float* __restrict__ S, const float* __restrict__ P,
    unsigned short* __restrict__ Mcat)
{
    const int z = blockIdx.y, h = blockIdx.x;
    __shared__ float As[CPH * CPH];
    const float* Sb = S + (size_t)(z * NHEADS + h) * CPH * CPH;
    for (int e = threadIdx.x; e < CPH * CPH; e += 256) As[e] = Sb[e];
    __syncthreads();
    unsigned short* Mz = Mcat + (size_t)z * CDIM * CDIM;
    for (int e = threadIdx.x; e < CDIM * CPH; e += 256) {
        const int m = e / CPH, d = e % CPH;
        const float* pr = P + (size_t)m * CDIM + h * CPH;
        float s = 0.f;
        #pragma unroll
        for (int c = 0; c < CPH; ++c) s = fmaf(pr[c], As[c * CPH + d], s);
        Mz[(size_t)m * CDIM + h * CPH + d] = f2bf(s);
    }
}

extern "C" void kernel_launch(void* const* d_in, const int* in_sizes, int n_in,
                              void* d_out, int out_size, void* d_ws, size_t ws_size,
                              hipStream_t stream)
{
    const float* x      = (const float*)d_in[0];
    const int*   mask   = (const int*)d_in[1];
    const float* qkv_w  = (const float*)d_in[2];
    const float* dw_w   = (const float*)d_in[3];
    const float* proj_w = (const float*)d_in[4];
    const float* temp   = (const float*)d_in[5];
    const float* wblend = (const float*)d_in[6];
    const float* pos_w1 = (const float*)d_in[7];
    const float* pos_w2 = (const float*)d_in[8];
    float* out = (float*)d_out;

    auto need = [](size_t nb) {
        return nb * ((size_t)NPIX * CDIM * 2
                   + (size_t)C3 * NPIX * 2
                   + (size_t)C3 * NPIX * 2
                   + (size_t)NHEADS * CPH * CPH * 4
                   + (size_t)2 * CDIM * 4
                   + (size_t)CDIM * CDIM * 2)
             + (size_t)C3 * CDIM * 2;
    };
    int nb = 4;
    if (need(4) > ws_size) nb = (need(2) <= ws_size) ? 2 : 1;

    char* p = (char*)d_ws;
    unsigned short* w_bf  = (unsigned short*)p; p += (size_t)C3 * CDIM * 2;
    unsigned short* x_t   = (unsigned short*)p; p += (size_t)nb * NPIX * CDIM * 2;
    unsigned short* qkv0  = (unsigned short*)p; p += (size_t)nb * C3 * NPIX * 2;
    unsigned short* qkvdw = (unsigned short*)p; p += (size_t)nb * C3 * NPIX * 2;
    float* S      = (float*)p; p += (size_t)nb * NHEADS * CPH * CPH * 4;
    float* norms2 = (float*)p; p += (size_t)nb * 2 * CDIM * 4;
    unsigned short* Mcat = (unsigned short*)p;
    unsigned short* v_t = qkv0;                   // alias: qkv0 dead by then
    _Float16* attn_h = (_Float16*)x_t;            // alias: x_t dead after qkv GEMM

    cast_bf16_kernel<<<dim3(C3 * CDIM / 4 / 256), 256, 0, stream>>>(qkv_w, w_bf, C3 * CDIM / 4);

    for (int b0 = 0; b0 < 4; b0 += nb) {
        const float* xb = x + (size_t)b0 * CDIM * NPIX;
        float* outb = out + (size_t)b0 * CDIM * NPIX;

        hipMemsetAsync(S, 0, (size_t)nb * NHEADS * CPH * CPH * 4, stream);
        hipMemsetAsync(norms2, 0, (size_t)nb * 2 * CDIM * 4, stream);

        // x -> bf16 x^T [n][k]
        transpose_kernel<0><<<dim3(NPIX / 64, CDIM / 64, nb), 256, 0, stream>>>(
            xb, x_t, (size_t)CDIM * NPIX);
        // qkv 1x1 conv: bf16 MFMA GEMM -> qkv0 bf16
        mfma_gemm_kernel<1, 0><<<dim3(NPIX / 128, C3 / 128, nb), 256, 0, stream>>>(
            w_bf, x_t, qkv0, C3);
        // depthwise 3x3 on all 1152 ch + fused q/k sum-of-squares
        dwconv_fast_kernel<<<dim3(4, C3, nb), 256, 0, stream>>>(
            qkv0, dw_w, qkvdw, norms2);
        // raw scores
        scores_mfma_kernel<<<dim3(8, NHEADS, nb), 256, 0, stream>>>(qkvdw, S);
        // dual-softmax blend
        softmax_kernel<<<dim3(CPH, NHEADS, nb), 64, 0, stream>>>(
            S, norms2, mask, temp, wblend);
        // fold proj into attn: Mcat = [P_h @ A_h]
        mproj_kernel<<<dim3(NHEADS, nb), 256, 0, stream>>>(S, proj_w, Mcat);
        // v -> bf16 v^T [n][k]
        transpose_kernel<1><<<dim3(NPIX / 64, CDIM / 64, nb), 256, 0, stream>>>(
            qkvdw + (size_t)2 * CDIM * NPIX, v_t, (size_t)C3 * NPIX);
        // fused attn@v + proj -> fp16 scratch
        mfma_gemm_kernel<2, 1><<<dim3(NPIX / 128, CDIM / 128, nb), 256, 0, stream>>>(
            Mcat, v_t, attn_h, CDIM);
        // pos branch + final combine: out = attn + dw(gelu(dw(v)))  (pure write)
        pos_fused_kernel<<<dim3(4, CDIM, nb), 256, 0, stream>>>(
            qkvdw, attn_h, pos_w1, pos_w2, outb);
    }
}